// Round 5
// baseline (680.818 us; speedup 1.0000x reference)
//
#include <hip/hip_runtime.h>

// QLSTM: B=512, T=1024, IN=1, H=64.
// R5 restructure: SPLIT-K, 8 waves per batch element (block=512):
//   wave w -> gate (w&3), k-half (w>>2). Lane l owns hidden unit l.
//   Each lane holds 32 recurrent weights (8 float4) -> ~50 VGPRs total,
//   UNDER the 64-reg occupancy bucket, so the allocator keeps them resident
//   naturally (R0-R4 showed it refuses to hold 64 at any hint/pin).
// Occupancy: 512 blocks x 8 waves = 16 waves/CU = 4/SIMD (was 2/SIMD) ->
//   the serial-chain stalls (LDS round trips, barrier, transcendentals)
//   now overlap across independent blocks.
//
// Sync structure (1 barrier/step), generalizing the verified 4-wave kernel:
//  - partial dot products exchanged via DOUBLE-BUFFERED part[t&1][8][64];
//    write -> barrier -> read. Parity prevents WAR without a 2nd barrier
//    (fast wave's next write targets the other parity; it cannot lap the
//    slow wave past the next barrier).
//  - every wave redundantly computes the c,h update for its lane's unit
//    (gsum = partA + partB per gate) -- small VALU tail, no 2nd barrier.
//  - each wave keeps a PRIVATE LDS h copy hs[w][64]; same-wave write->read
//    ordering needs no barrier. Dot reads only its own k-half (8 b128
//    same-address broadcasts).
//
// Numerics: gate sum order changes to (bias + x*u + sum(k<32)) + sum(k>=32)
// (~1e-7 reorder). Harness already passes hw-rcp/__expf at absmax 0.0, so
// this is within the checker's tolerance envelope.

#define TLEN 1024
#define HID  64

__device__ __forceinline__ float fast_sigmoid(float x) {
    return __builtin_amdgcn_rcpf(1.0f + __expf(-x));   // hw exp + hw rcp
}
__device__ __forceinline__ float fast_tanh(float x) {
    return __builtin_fmaf(2.0f, fast_sigmoid(2.0f * x), -1.0f);
}

__global__ __launch_bounds__(512, 4)   // 4 waves/EU min -> 2 blocks/CU, VGPR cap 128
void qlstm_kernel(const float* __restrict__ x,      // [B, T, 1]
                  const float* __restrict__ W_ih,   // [256, 1]
                  const float* __restrict__ W_hh,   // [256, 64]
                  const float* __restrict__ b_ih,   // [256]
                  const float* __restrict__ b_hh,   // [256]
                  const float* __restrict__ W_lin,  // [1, 64]
                  const float* __restrict__ b_lin,  // [1]
                  float* __restrict__ out)          // [B]
{
    const int b    = blockIdx.x;
    const int tid  = threadIdx.x;
    const int w    = tid >> 6;        // wave 0..7
    const int g    = w & 3;           // gate: i,f,g,o
    const int half = w >> 2;          // k-half: 0 -> k<32, 1 -> k>=32
    const int l    = tid & 63;        // hidden unit

    __shared__ __align__(16) float xs[TLEN];          // 4 KB
    __shared__ __align__(16) float hs[8][HID];        // 2 KB  per-wave private h
    __shared__ __align__(16) float part[2][8][HID];   // 4 KB  double-buffered partials

    // Stage x row: 1024 floats / 512 threads = one float2 each (coalesced).
    ((float2*)xs)[tid] = ((const float2*)(x + (size_t)b * TLEN))[tid];

    // This wave's 32 weights: W_hh[g*64+l][32*half .. 32*half+32).
    const int row = g * HID + l;
    const float4* Wr = (const float4*)(W_hh + (size_t)row * HID + 32 * half);
    float4 wq[8];
    #pragma unroll
    for (int q = 0; q < 8; ++q) wq[q] = Wr[q];

    const float u    = W_ih[row];                 // IN == 1
    const float bias = b_ih[row] + b_hh[row];
    const float wlin = W_lin[l];

    float c = 0.0f, h = 0.0f;
    hs[w][l] = 0.0f;
    __syncthreads();   // xs + hs ready

    const float* hsw = &hs[w][32 * half];   // this wave's k-half of its h copy

    for (int t = 0; t < TLEN; ++t) {
        const int p = t & 1;
        const float xt = xs[t];               // same-address broadcast

        // Partial dot: bias + x*u only in half 0 (preserves per-half serial order).
        float acc = (half == 0) ? __builtin_fmaf(xt, u, bias) : 0.0f;
        #pragma unroll
        for (int q = 0; q < 8; ++q) {
            const float4 hk = *(const float4*)&hsw[4 * q];   // b128 broadcast
            acc = __builtin_fmaf(hk.x, wq[q].x, acc);
            acc = __builtin_fmaf(hk.y, wq[q].y, acc);
            acc = __builtin_fmaf(hk.z, wq[q].z, acc);
            acc = __builtin_fmaf(hk.w, wq[q].w, acc);
        }
        part[p][w][l] = acc;                  // stride-1, 2 lanes/bank (free)
        __syncthreads();                      // the ONE barrier per step

        // Redundant (x8 waves) but tiny: gate sums + activations + c,h update.
        const float gi = part[p][0][l] + part[p][4][l];
        const float gf = part[p][1][l] + part[p][5][l];
        const float gg = part[p][2][l] + part[p][6][l];
        const float go = part[p][3][l] + part[p][7][l];
        const float ai = fast_sigmoid(gi);
        const float af = fast_sigmoid(gf);
        const float ag = fast_tanh(gg);
        const float ao = fast_sigmoid(go);
        c = __builtin_fmaf(af, c, ai * ag);
        h = ao * fast_tanh(c);
        hs[w][l] = h;                         // private copy; no barrier
    }

    // out[b] = dot(h, W_lin) + b_lin  (wave 0 only; lane l holds h_l)
    if (w == 0) {
        float v = h * wlin;
        #pragma unroll
        for (int off = 32; off > 0; off >>= 1)
            v += __shfl_down(v, off, 64);
        if (l == 0) out[b] = v + b_lin[0];
    }
}

extern "C" void kernel_launch(void* const* d_in, const int* in_sizes, int n_in,
                              void* d_out, int out_size, void* d_ws, size_t ws_size,
                              hipStream_t stream) {
    const float* x     = (const float*)d_in[0];
    const float* W_ih  = (const float*)d_in[1];
    const float* W_hh  = (const float*)d_in[2];
    const float* b_ih  = (const float*)d_in[3];
    const float* b_hh  = (const float*)d_in[4];
    const float* W_lin = (const float*)d_in[5];
    const float* b_lin = (const float*)d_in[6];
    float* out = (float*)d_out;

    const int B = out_size;  // 512
    qlstm_kernel<<<B, 512, 0, stream>>>(x, W_ih, W_hh, b_ih, b_hh, W_lin, b_lin, out);
}